// Round 1
// baseline (9675.169 us; speedup 1.0000x reference)
//
#include <hip/hip_runtime.h>
#include <stdint.h>

namespace {
constexpr int kB = 64, kT = 200;
constexpr int kNin = 700, kNs = 50, kNz = 100, kNh = 512, kNho = 100, kNout = 20;
constexpr float kDecay = 0.95f, kThresh = 0.5f, kRefrac = 2.0f;
}

// Adaptive-LIF update (REST=RESET=0, DT=1): returns spike flag via ref.
__device__ __forceinline__ void lif(float& v, float& r, float x, bool& spk) {
    r = fmaxf(r - 1.0f, 0.0f);
    v = kDecay * v + (r <= 0.0f ? x : 0.0f);
    spk = (v >= kThresh);
    if (spk) { v = 0.0f; r = kRefrac; }
}

// Deterministic sparse row-sum: sum_{i in lst[0..cnt)} W[i*ld + j]
__device__ __forceinline__ float rowsum(const unsigned short* __restrict__ lst, int cnt,
                                        const float* __restrict__ W, int ld, int j) {
    float a0 = 0.f, a1 = 0.f, a2 = 0.f, a3 = 0.f;
    int q = 0;
    for (; q + 4 <= cnt; q += 4) {
        const int i0 = lst[q], i1 = lst[q + 1], i2 = lst[q + 2], i3 = lst[q + 3];
        a0 += W[i0 * ld + j];
        a1 += W[i1 * ld + j];
        a2 += W[i2 * ld + j];
        a3 += W[i3 * ld + j];
    }
    for (; q < cnt; ++q) a0 += W[lst[q] * ld + j];
    return (a0 + a1) + (a2 + a3);
}

__global__ __launch_bounds__(512, 1)
void snn_seq(const float* __restrict__ x_in, const float* __restrict__ W_i,
             const float* __restrict__ W_z, const float* __restrict__ W_c,
             const float* __restrict__ W_h, const float* __restrict__ W_ho,
             const float* __restrict__ W_o, const float* __restrict__ lam_p,
             const float* __restrict__ eta_p, float* __restrict__ out) {
    __shared__ float lampow[kT];
    __shared__ float ck[kT];
    __shared__ __align__(16) float prevh[kNh];     // h_new state (float), also stage-7 input
    __shared__ float xi_red[10][kNs];
    __shared__ float ho_red[5][kNho];
    __shared__ unsigned long long hist[kT][8];     // spike-history bitmasks of h
    __shared__ unsigned long long zmask[2], omask[2];
    __shared__ unsigned short idx_s[kNs], idx_z[kNz], idx_h[kNh], idx_o[kNho];
    __shared__ int cnt_s, cnt_z, cnt_h, cnt_o;

    const int tid = threadIdx.x;
    const int b = blockIdx.x;
    const float lam = lam_p[0], eta = eta_p[0];

    if (tid == 0) {
        float p = 1.0f;
        for (int i = 0; i < kT; ++i) { lampow[i] = p; p *= lam; }
    }
    for (int i = tid; i < kNh; i += 512) prevh[i] = 0.0f;

    // Per-thread register states (thread j owns neuron j of each population).
    float vs = 0, rs = 0, vz = 0, rz = 0, vh = 0, rh = 0, vho = 0, rho = 0, vo = 0, ro = 0;

    __syncthreads();

    for (int t = 0; t < kT; ++t) {
        const float* xt = x_in + ((size_t)t * kB + b) * kNin;

        // ---- A: xi = x @ W_i partials (10 groups of 70 rows x 50 outputs)
        if (tid < 500) {
            const int g = tid / kNs, j = tid - g * kNs;
            const float* wp = W_i + j;
            const int i0 = g * 70;
            float a0 = 0.f, a1 = 0.f;
            for (int i = i0; i < i0 + 70; i += 2) {
                a0 = fmaf(xt[i], wp[i * kNs], a0);
                a1 = fmaf(xt[i + 1], wp[(i + 1) * kNs], a1);
            }
            xi_red[g][j] = a0 + a1;
        }
        __syncthreads();

        // ---- B: s-LIF + s index list (all s neurons live in wave 0)
        bool sspk = false;
        if (tid < kNs) {
            float x = 0.f;
            for (int g = 0; g < 10; ++g) x += xi_red[g][tid];
            lif(vs, rs, x, sspk);
        }
        {
            const unsigned long long sm = __ballot(sspk);
            if (tid < kNs) {
                if (sspk) {
                    const int pos = __popcll(sm & ((1ull << tid) - 1));
                    idx_s[pos] = (unsigned short)tid;
                }
                if (tid == 0) cnt_s = __popcll(sm);
            }
        }
        __syncthreads();

        // ---- D: z = lif(rowsum_s(W_z))
        bool zspk = false;
        if (tid < kNz) {
            const float x = rowsum(idx_s, cnt_s, W_z, kNz, tid);
            lif(vz, rz, x, zspk);
        }
        {
            const unsigned long long zm = __ballot(zspk);
            if ((tid & 63) == 0 && tid < kNz) zmask[tid >> 6] = zm;
        }
        __syncthreads();

        // ---- E: z index list
        if (tid < kNz) {
            const int w = tid >> 6, bit = tid & 63;
            const unsigned long long mw = zmask[w];
            if ((mw >> bit) & 1) {
                int pos = __popcll(mw & ((1ull << bit) - 1));
                if (w) pos += __popcll(zmask[0]);
                idx_z[pos] = (unsigned short)tid;
            }
            if (tid == 0) cnt_z = __popcll(zmask[0]) + __popcll(zmask[1]);
        }
        __syncthreads();

        // ---- F: cz (sparse) + dense prevh @ W_h column dot; h-LIF; history ballot
        const float czv = rowsum(idx_z, cnt_z, W_c, kNh, tid);
        const float* wh = W_h + tid;
        float a0 = 0.f, a1 = 0.f, a2 = 0.f, a3 = 0.f;
        for (int i = 0; i < kNh; i += 8) {
            const float4 p0 = *(const float4*)&prevh[i];
            const float4 p1 = *(const float4*)&prevh[i + 4];
            a0 = fmaf(p0.x, wh[(i + 0) * kNh], a0);
            a1 = fmaf(p0.y, wh[(i + 1) * kNh], a1);
            a2 = fmaf(p0.z, wh[(i + 2) * kNh], a2);
            a3 = fmaf(p0.w, wh[(i + 3) * kNh], a3);
            a0 = fmaf(p1.x, wh[(i + 4) * kNh], a0);
            a1 = fmaf(p1.y, wh[(i + 5) * kNh], a1);
            a2 = fmaf(p1.z, wh[(i + 6) * kNh], a2);
            a3 = fmaf(p1.w, wh[(i + 7) * kNh], a3);
        }
        bool hspk = false;
        lif(vh, rh, czv + ((a0 + a1) + (a2 + a3)), hspk);
        {
            const unsigned long long hm = __ballot(hspk);
            if ((tid & 63) == 0) hist[t][tid >> 6] = hm;
        }
        __syncthreads();

        // ---- G: recall coefficients c_k = eta*lam^(t-k)*(h_t . h_k)  (exact popcount)
        if (tid <= t) {
            const unsigned long long* ht = hist[t];
            const unsigned long long* hk = hist[tid];
            int d = 0;
#pragma unroll
            for (int w = 0; w < 8; ++w) d += __popcll(ht[w] & hk[w]);
            ck[tid] = eta * lampow[t - tid] * (float)d;
        }
        {
            const int w = tid >> 6, bit = tid & 63;
            const unsigned long long mw = hist[t][w];
            if ((mw >> bit) & 1) {
                int pos = __popcll(mw & ((1ull << bit) - 1));
                for (int u = 0; u < w; ++u) pos += __popcll(hist[t][u]);
                idx_h[pos] = (unsigned short)tid;
            }
            if (tid == 0) {
                int c = 0;
#pragma unroll
                for (int u = 0; u < 8; ++u) c += __popcll(hist[t][u]);
                cnt_h = c;
            }
        }
        __syncthreads();

        // ---- H: recall r_j = sum_k c_k * h_k[j]; h_new = (h@W_h + cz) + r
        {
            const int w = tid >> 6, bit = tid & 63;
            float racc = 0.f;
            for (int k = 0; k <= t; ++k) {
                const float c = ck[k];
                if (c != 0.0f) racc += ((hist[k][w] >> bit) & 1) ? c : 0.0f;
            }
            const float hw = rowsum(idx_h, cnt_h, W_h, kNh, tid);
            prevh[tid] = (hw + czv) + racc;
        }
        __syncthreads();

        // ---- I: h_new @ W_ho partials (5 groups x 100 outputs)
        if (tid < 500) {
            const int g = tid / kNho, j = tid - g * kNho;
            const int i0 = g * 103;
            const int i1 = (g == 4) ? kNh : i0 + 103;
            const float* wp = W_ho + j;
            float s0 = 0.f, s1 = 0.f;
            int i = i0;
            for (; i + 2 <= i1; i += 2) {
                s0 = fmaf(prevh[i], wp[i * kNho], s0);
                s1 = fmaf(prevh[i + 1], wp[(i + 1) * kNho], s1);
            }
            if (i < i1) s0 = fmaf(prevh[i], wp[i * kNho], s0);
            ho_red[g][j] = s0 + s1;
        }
        __syncthreads();

        // ---- J: o-LIF
        bool ospk = false;
        if (tid < kNho) {
            const float x = ((ho_red[0][tid] + ho_red[1][tid]) +
                             (ho_red[2][tid] + ho_red[3][tid])) + ho_red[4][tid];
            lif(vho, rho, x, ospk);
        }
        {
            const unsigned long long om = __ballot(ospk);
            if ((tid & 63) == 0 && tid < kNho) omask[tid >> 6] = om;
        }
        __syncthreads();

        // ---- K: o index list
        if (tid < kNho) {
            const int w = tid >> 6, bit = tid & 63;
            const unsigned long long mw = omask[w];
            if ((mw >> bit) & 1) {
                int pos = __popcll(mw & ((1ull << bit) - 1));
                if (w) pos += __popcll(omask[0]);
                idx_o[pos] = (unsigned short)tid;
            }
            if (tid == 0) cnt_o = __popcll(omask[0]) + __popcll(omask[1]);
        }
        __syncthreads();

        // ---- L: y = lif(rowsum_o(W_o)); write output spikes
        if (tid < kNout) {
            const float x = rowsum(idx_o, cnt_o, W_o, kNout, tid);
            bool yspk = false;
            lif(vo, ro, x, yspk);
            out[((size_t)t * kB + b) * kNout + tid] = yspk ? 1.0f : 0.0f;
        }
        // no trailing barrier needed: next stage-A writes xi_red, which was last
        // read before two barriers ago; all other buffers are barrier-separated.
    }
}

extern "C" void kernel_launch(void* const* d_in, const int* in_sizes, int n_in,
                              void* d_out, int out_size, void* d_ws, size_t ws_size,
                              hipStream_t stream) {
    const float* x_in = (const float*)d_in[0];
    const float* W_i  = (const float*)d_in[1];
    const float* W_z  = (const float*)d_in[2];
    const float* W_c  = (const float*)d_in[3];
    const float* W_h  = (const float*)d_in[4];
    const float* W_ho = (const float*)d_in[5];
    const float* W_o  = (const float*)d_in[6];
    const float* lam  = (const float*)d_in[7];
    const float* eta  = (const float*)d_in[8];
    snn_seq<<<kB, 512, 0, stream>>>(x_in, W_i, W_z, W_c, W_h, W_ho, W_o, lam, eta,
                                    (float*)d_out);
}